// Round 8
// baseline (981.743 us; speedup 1.0000x reference)
//
#include <hip/hip_runtime.h>
#include <hip/hip_bf16.h>

#define NN 50000    // nodes
#define NE 100000   // edges
#define NG 2048     // graphs
#define NF 14
#define D 64
#define EB 256      // edges per block in msg kernel

typedef __attribute__((ext_vector_type(8))) short bf16x8;
typedef __attribute__((ext_vector_type(4))) float f32x4;

__device__ __forceinline__ float sigmoidf(float x) { return 1.f / (1.f + expf(-x)); }

// ---------------- utility ----------------
__global__ void cvt_bf16_kernel(const float* __restrict__ src, __hip_bfloat16* __restrict__ dst, int n) {
    int i = blockIdx.x * 256 + threadIdx.x;
    if (i < n) dst[i] = __float2bfloat16(src[i]);
}

// dst[c*rows + r] = src[r*cols + c]
__global__ void transpose_kernel(const float* __restrict__ src, float* __restrict__ dst,
                                 int rows, int cols) {
    int idx = blockIdx.x * 256 + threadIdx.x;
    if (idx < rows * cols) {
        int r = idx / cols, c = idx - r * cols;
        dst[c * rows + r] = src[idx];
    }
}

// ---------------- lin0: out = relu(x @ lin0_w.T + b) ----------------
__global__ void lin0_kernel(const float* __restrict__ x, const float* __restrict__ w,
                            const float* __restrict__ b, float* __restrict__ out) {
    int grp = threadIdx.x >> 6;
    int d = threadIdx.x & 63;
    int n = blockIdx.x * 4 + grp;
    __shared__ float xs[4][NF];
    int t = threadIdx.x;
    if (t < 4 * NF) {
        int r = t / NF, c = t - r * NF;
        int nn2 = blockIdx.x * 4 + r;
        xs[r][c] = (nn2 < NN) ? x[nn2 * NF + c] : 0.f;
    }
    __syncthreads();
    if (n >= NN) return;
    float acc = b[d];
#pragma unroll
    for (int k = 0; k < NF; k++) acc += xs[grp][k] * w[d * NF + k];
    out[n * D + d] = fmaxf(acc, 0.f);
}

// ================= MFMA fused message kernel v4: barrier-free i-loop =================
// 512 threads = 8 waves. wave = (half = wid>>2: edges half*128..+127, ct = wid&3: o-cols ct*16..+15).
// Each wave: 8 row-tiles. B-fragments read DIRECTLY from L2-resident w2r (no LDS staging,
// no barriers in the i-loop). S[rt] per i via MFMA; acc[rt] += h[src,i] * S[rt].
__global__ __launch_bounds__(512, 2) void msg_mfma_kernel(
    const float* __restrict__ h, const float* __restrict__ ea,
    const float* __restrict__ w1, const float* __restrict__ b1,
    const __hip_bfloat16* __restrict__ w2r,  // bf16 nn_w2 [4096][128] row-major = [i][o][k]
    const float* __restrict__ b2, const int* __restrict__ ei,
    float* __restrict__ agg)
{
    // pool: hid[256][132] bf16 (preamble) aliases B2s[64][72] bf16 (b2 pass)
    __shared__ __align__(16) char pool[67584];
    __hip_bfloat16 (*hid)[132] = (__hip_bfloat16(*)[132])pool;
    __hip_bfloat16 (*B2s)[72] = (__hip_bfloat16(*)[72])pool;
    __shared__ __align__(16) float hsT[64][260];  // hsT[i][e] = h[src_e][i] f32
    __shared__ float w1s[128][4];
    __shared__ float b1s[128];
    __shared__ int didx[EB];

    int tid = threadIdx.x;
    int e0 = blockIdx.x * EB;

    if (tid < 128) {
        w1s[tid][0] = w1[tid * 4 + 0]; w1s[tid][1] = w1[tid * 4 + 1];
        w1s[tid][2] = w1[tid * 4 + 2]; w1s[tid][3] = w1[tid * 4 + 3];
        b1s[tid] = b1[tid];
    }
    if (tid < EB) didx[tid] = (e0 + tid < NE) ? ei[NE + e0 + tid] : -1;
    // --- gather h[src] -> hsT f32; 2 threads per edge, 32 i each ---
    {
        int e = tid >> 1, half = (tid & 1) * 32;
        int ge = e0 + e;
        int src = (ge < NE) ? ei[ge] : 0;
        const float4* hp = (const float4*)(h + (size_t)src * 64 + half);
#pragma unroll
        for (int u = 0; u < 8; u++) {
            float4 v = (ge < NE) ? hp[u] : make_float4(0.f, 0.f, 0.f, 0.f);
            hsT[half + u * 4 + 0][e] = v.x;
            hsT[half + u * 4 + 1][e] = v.y;
            hsT[half + u * 4 + 2][e] = v.z;
            hsT[half + u * 4 + 3][e] = v.w;
        }
    }
    __syncthreads();  // w1s/b1s ready
    // --- hid[e][k] = relu(b1[k] + ea[e]·w1[k]) bf16; 2 threads per edge, 64 k each ---
    {
        int e = tid & 255, kb = (tid >> 8) * 64;
        int ge = e0 + e;
        float4 av = (ge < NE) ? *(const float4*)(ea + (size_t)ge * 4)
                              : make_float4(0.f, 0.f, 0.f, 0.f);
        for (int k = kb; k < kb + 64; k += 4) {
            union { __hip_bfloat16 b[4]; uint2 uu; } pk;
#pragma unroll
            for (int u = 0; u < 4; u++) {
                float v = b1s[k + u] + av.x * w1s[k + u][0] + av.y * w1s[k + u][1] +
                          av.z * w1s[k + u][2] + av.w * w1s[k + u][3];
                pk.b[u] = __float2bfloat16((ge < NE) ? fmaxf(v, 0.f) : 0.f);
            }
            *(uint2*)&hid[e][k] = pk.uu;
        }
    }
    __syncthreads();  // hid ready

    int lane = tid & 63;
    int wid = tid >> 6;
    int half = wid >> 2;        // edge half: rows half*128 .. +127
    int ct = wid & 3;           // o-col tile
    int n = lane & 15, q = lane >> 4;
    int ocol = ct * 16 + n;

    // A-fragments (i-invariant): 8 row-tiles x 4 k-steps = 128 VGPR
    bf16x8 afr[8][4];
#pragma unroll
    for (int rt = 0; rt < 8; rt++)
#pragma unroll
        for (int ks = 0; ks < 4; ks++)
            afr[rt][ks] = *(const bf16x8*)&hid[half * 128 + rt * 16 + n][ks * 32 + q * 8];
    // NO barrier: hid stays valid until the post-loop barrier; B2s aliasing happens after it.

    // B-frag global base for this lane: element (i*64 + ocol)*128 + ks*32 + q*8
    const __hip_bfloat16* bptr = w2r + (size_t)ocol * 128 + q * 8;

    f32x4 acc[8];
#pragma unroll
    for (int rt = 0; rt < 8; rt++) acc[rt] = (f32x4){0.f, 0.f, 0.f, 0.f};

    // preload i=0 fragments
    bf16x8 bcur[4], bnxt[4];
#pragma unroll
    for (int ks = 0; ks < 4; ks++) bcur[ks] = *(const bf16x8*)(bptr + ks * 32);

    for (int i = 0; i < 64; i++) {
        if (i + 1 < 64) {
            const __hip_bfloat16* p = bptr + (size_t)(i + 1) * 8192;
#pragma unroll
            for (int ks = 0; ks < 4; ks++) bnxt[ks] = *(const bf16x8*)(p + ks * 32);
        }
        f32x4 S[8];
#pragma unroll
        for (int rt = 0; rt < 8; rt++) S[rt] = (f32x4){0.f, 0.f, 0.f, 0.f};
#pragma unroll
        for (int ks = 0; ks < 4; ks++)
#pragma unroll
            for (int rt = 0; rt < 8; rt++)
                S[rt] = __builtin_amdgcn_mfma_f32_16x16x32_bf16(afr[rt][ks], bcur[ks], S[rt], 0, 0, 0);
        // fixup: acc[rt] += h[src, i] * S[rt]
#pragma unroll
        for (int rt = 0; rt < 8; rt++) {
            f32x4 hm = *(const f32x4*)&hsT[i][half * 128 + rt * 16 + q * 4];
#pragma unroll
            for (int r = 0; r < 4; r++) acc[rt][r] += hm[r] * S[rt][r];
        }
#pragma unroll
        for (int ks = 0; ks < 4; ks++) bcur[ks] = bnxt[ks];
    }

    __syncthreads();  // everyone past afr/hsT main use; pool can become B2s
    // ---- b2 pass: acc[e,o] += sum_i h[src_e,i] * b2[i*64+o] via MFMA ----
    for (int g2 = tid; g2 < 4096; g2 += 512) {
        B2s[g2 & 63][g2 >> 6] = __float2bfloat16(b2[g2]);
    }
    __syncthreads();
#pragma unroll
    for (int rt = 0; rt < 8; rt++) {
        f32x4 S2 = (f32x4){0.f, 0.f, 0.f, 0.f};
#pragma unroll
        for (int ks2 = 0; ks2 < 2; ks2++) {
            union { __hip_bfloat16 b[8]; bf16x8 v; } pk;
#pragma unroll
            for (int j = 0; j < 8; j++)
                pk.b[j] = __float2bfloat16(hsT[ks2 * 32 + q * 8 + j][half * 128 + rt * 16 + n]);
            bf16x8 bfr2 = *(const bf16x8*)&B2s[ocol][ks2 * 32 + q * 8];
            S2 = __builtin_amdgcn_mfma_f32_16x16x32_bf16(pk.v, bfr2, S2, 0, 0, 0);
        }
#pragma unroll
        for (int r = 0; r < 4; r++) acc[rt][r] += S2[r];
    }

    // scatter
#pragma unroll
    for (int rt = 0; rt < 8; rt++)
#pragma unroll
        for (int r = 0; r < 4; r++) {
            int e = half * 128 + rt * 16 + q * 4 + r;
            int dn = didx[e];
            if (dn >= 0) atomicAdd(&agg[(size_t)dn * 64 + ocol], acc[rt][r]);
        }
}

// ---------------- degree ----------------
__global__ void deg_kernel(const int* __restrict__ ei, float* __restrict__ deg) {
    int e = blockIdx.x * 256 + threadIdx.x;
    if (e < NE) atomicAdd(&deg[ei[NE + e]], 1.0f);
}
__global__ void invdeg_kernel(float* deg) {
    int n = blockIdx.x * 256 + threadIdx.x;
    if (n < NN) deg[n] = 1.0f / fmaxf(deg[n], 1.0f);
}

// ---------------- fused conv + GRU: 32 nodes/block ----------------
__global__ __launch_bounds__(512) void conv_gru_kernel(
    float* __restrict__ h, const float* __restrict__ agg, const float* __restrict__ invdeg,
    const float* __restrict__ root, const float* __restrict__ cbias,
    const float* __restrict__ wihT, const float* __restrict__ whhT,
    const float* __restrict__ bih, const float* __restrict__ bhh)
{
    int tid = threadIdx.x;
    int grp = tid >> 6;       // 0..7
    int j = tid & 63;
    int n0 = blockIdx.x * 32;
    int nd0 = grp * 4;
    __shared__ float hs[32][64];
    __shared__ float ms[32][68];
    for (int i = tid; i < 2048; i += 512) {
        int nd = i >> 6, dd = i & 63;
        int nn2 = n0 + nd;
        hs[nd][dd] = (nn2 < NN) ? h[(size_t)nn2 * D + dd] : 0.f;
    }
    __syncthreads();
    float mm[4] = {};
#pragma unroll 8
    for (int k = 0; k < 64; k++) {
        float rv = root[k * 64 + j];
#pragma unroll
        for (int q = 0; q < 4; q++) mm[q] += hs[nd0 + q][k] * rv;
    }
    float cb = cbias[j];
#pragma unroll
    for (int q = 0; q < 4; q++) {
        int nn2 = n0 + nd0 + q;
        float v = 0.f;
        if (nn2 < NN) v = fmaxf(mm[q] + agg[(size_t)nn2 * 64 + j] * invdeg[nn2] + cb, 0.f);
        ms[nd0 + q][j] = v;
    }
    __syncthreads();
    float air[4] = {}, aiz[4] = {}, ain[4] = {};
    float ahr[4] = {}, ahz[4] = {}, ahn[4] = {};
#pragma unroll 4
    for (int k = 0; k < 64; k++) {
        float wr = wihT[k * 192 + j];
        float wz = wihT[k * 192 + 64 + j];
        float wn = wihT[k * 192 + 128 + j];
        float vr = whhT[k * 192 + j];
        float vz = whhT[k * 192 + 64 + j];
        float vn = whhT[k * 192 + 128 + j];
#pragma unroll
        for (int q = 0; q < 4; q++) {
            float mv = ms[nd0 + q][k], hv = hs[nd0 + q][k];
            air[q] = fmaf(mv, wr, air[q]);
            aiz[q] = fmaf(mv, wz, aiz[q]);
            ain[q] = fmaf(mv, wn, ain[q]);
            ahr[q] = fmaf(hv, vr, ahr[q]);
            ahz[q] = fmaf(hv, vz, ahz[q]);
            ahn[q] = fmaf(hv, vn, ahn[q]);
        }
    }
    float br = bih[j], bz = bih[64 + j], bn = bih[128 + j];
    float cr = bhh[j], cz = bhh[64 + j], cn = bhh[128 + j];
#pragma unroll
    for (int q = 0; q < 4; q++) {
        int nn2 = n0 + nd0 + q;
        if (nn2 >= NN) continue;
        float r = sigmoidf(air[q] + br + ahr[q] + cr);
        float z = sigmoidf(aiz[q] + bz + ahz[q] + cz);
        float nv = tanhf(ain[q] + bn + r * (ahn[q] + cn));
        float hv = hs[nd0 + q][j];
        h[(size_t)nn2 * D + j] = (1.f - z) * nv + z * hv;
    }
}

// ---------------- graph starts (batch sorted) ----------------
__global__ void starts_kernel(const int* __restrict__ batch, int* __restrict__ start) {
    int n = blockIdx.x * 256 + threadIdx.x;
    if (n >= NN) return;
    int b = batch[n];
    int bp = (n == 0) ? -1 : batch[n - 1];
    for (int g = bp + 1; g <= b; g++) start[g] = n;
    if (n == NN - 1) {
        for (int g = b + 1; g <= NG; g++) start[g] = NN;
    }
}

// ---------------- Set2Set LSTM step ----------------
__global__ void s2s_lstm_kernel(const float* __restrict__ qstar, float* __restrict__ hh,
                                float* __restrict__ cc, const float* __restrict__ wihT,
                                const float* __restrict__ whhT, const float* __restrict__ bih,
                                const float* __restrict__ bhh) {
    int g = blockIdx.x;
    int j = threadIdx.x;  // 256
    __shared__ float q[128], hsh[64], gates[256];
    if (j < 128) q[j] = qstar[g * 128 + j];
    if (j < 64) hsh[j] = hh[g * 64 + j];
    __syncthreads();
    float acc = bih[j] + bhh[j];
#pragma unroll 8
    for (int k = 0; k < 128; k++) acc = fmaf(q[k], wihT[k * 256 + j], acc);
#pragma unroll 8
    for (int k = 0; k < 64; k++) acc = fmaf(hsh[k], whhT[k * 256 + j], acc);
    gates[j] = acc;
    __syncthreads();
    if (j < 64) {
        float gi = gates[j], gf = gates[64 + j], gg = gates[128 + j], go = gates[192 + j];
        float c2 = sigmoidf(gf) * cc[g * 64 + j] + sigmoidf(gi) * tanhf(gg);
        float h2 = sigmoidf(go) * tanhf(c2);
        cc[g * 64 + j] = c2;
        hh[g * 64 + j] = h2;
    }
}

// ---------------- Set2Set attention + pooling; 4 node-groups per block ----------------
__global__ void s2s_attn_kernel(const float* __restrict__ out, const float* __restrict__ hh,
                                const int* __restrict__ start, float* __restrict__ qstar) {
    int g = blockIdx.x;
    int tid = threadIdx.x;  // 256
    int d = tid & 63, sub = tid >> 6;
    int n0 = start[g], n1 = start[g + 1];
    float hd = hh[g * 64 + d];
    __shared__ float red[4][64];
    __shared__ float mxS[4], seS[4];
    float mx = -INFINITY;
    for (int n = n0 + sub; n < n1; n += 4) {
        float p = out[n * D + d] * hd;
#pragma unroll
        for (int off = 32; off; off >>= 1) p += __shfl_xor(p, off);
        mx = fmaxf(mx, p);
    }
    if (d == 0) mxS[sub] = mx;
    __syncthreads();
    mx = fmaxf(fmaxf(mxS[0], mxS[1]), fmaxf(mxS[2], mxS[3]));
    float sexp = 0.f, racc = 0.f;
    for (int n = n0 + sub; n < n1; n += 4) {
        float ond = out[n * D + d];
        float p = ond * hd;
#pragma unroll
        for (int off = 32; off; off >>= 1) p += __shfl_xor(p, off);
        float a = expf(p - mx);
        sexp += a;
        racc = fmaf(a, ond, racc);
    }
    red[sub][d] = racc;
    if (d == 0) seS[sub] = sexp;
    __syncthreads();
    if (sub == 0) {
        float rtot = red[0][d] + red[1][d] + red[2][d] + red[3][d];
        float stot = seS[0] + seS[1] + seS[2] + seS[3];
        float r = rtot / (stot + 1e-16f);
        qstar[g * 128 + d] = hd;
        qstar[g * 128 + 64 + d] = r;
    }
}

// ---------------- head ----------------
__global__ void final_kernel(const float* __restrict__ qstar, const float* __restrict__ w1,
                             const float* __restrict__ b1, const float* __restrict__ w2,
                             const float* __restrict__ b2, float* __restrict__ y) {
    int g = blockIdx.x;
    int d = threadIdx.x;  // 64
    __shared__ float q[128];
    q[d] = qstar[g * 128 + d];
    q[64 + d] = qstar[g * 128 + 64 + d];
    __syncthreads();
    float acc = b1[d];
#pragma unroll 8
    for (int k = 0; k < 128; k++) acc = fmaf(q[k], w1[d * 128 + k], acc);
    acc = fmaxf(acc, 0.f);
    float p = acc * w2[d];
#pragma unroll
    for (int off = 32; off; off >>= 1) p += __shfl_xor(p, off);
    if (d == 0) y[g] = p + b2[0];
}

extern "C" void kernel_launch(void* const* d_in, const int* in_sizes, int n_in,
                              void* d_out, int out_size, void* d_ws, size_t ws_size,
                              hipStream_t stream) {
    (void)in_sizes; (void)n_in; (void)out_size; (void)ws_size;
    const float* x = (const float*)d_in[0];
    const int* edge_index = (const int*)d_in[1];
    const float* edge_attr = (const float*)d_in[2];
    const int* batch = (const int*)d_in[3];
    const float* lin0_w = (const float*)d_in[4];
    const float* lin0_b = (const float*)d_in[5];
    const float* nn_w1 = (const float*)d_in[6];
    const float* nn_b1 = (const float*)d_in[7];
    const float* nn_w2 = (const float*)d_in[8];
    const float* nn_b2 = (const float*)d_in[9];
    const float* conv_root = (const float*)d_in[10];
    const float* conv_bias = (const float*)d_in[11];
    const float* gru_w_ih = (const float*)d_in[12];
    const float* gru_w_hh = (const float*)d_in[13];
    const float* gru_b_ih = (const float*)d_in[14];
    const float* gru_b_hh = (const float*)d_in[15];
    const float* s2s_w_ih = (const float*)d_in[16];
    const float* s2s_w_hh = (const float*)d_in[17];
    const float* s2s_b_ih = (const float*)d_in[18];
    const float* s2s_b_hh = (const float*)d_in[19];
    const float* lin1_w = (const float*)d_in[20];
    const float* lin1_b = (const float*)d_in[21];
    const float* lin2_w = (const float*)d_in[22];
    const float* lin2_b = (const float*)d_in[23];
    float* y = (float*)d_out;

    char* ws = (char*)d_ws;
    size_t off = 0;
    auto alloc = [&](size_t bytes) {
        void* p = ws + off;
        off = (off + bytes + 255) & ~(size_t)255;
        return p;
    };
    float* h = (float*)alloc((size_t)NN * D * 4);
    float* agg = (float*)alloc((size_t)NN * D * 4);
    float* invdeg = (float*)alloc((size_t)NN * 4);
    int* start = (int*)alloc((size_t)(NG + 1) * 4);
    float* qstar = (float*)alloc((size_t)NG * 128 * 4);   // 1 MB; ALIASED as w2r during MP phase
    float* hh = (float*)alloc((size_t)NG * 64 * 4);
    float* ccv = (float*)alloc((size_t)NG * 64 * 4);
    float* gruT_ih = (float*)alloc(192 * 64 * 4);
    float* gruT_hh = (float*)alloc(192 * 64 * 4);
    float* s2sT_ih = (float*)alloc(256 * 128 * 4);
    float* s2sT_hh = (float*)alloc(256 * 64 * 4);
    // w2r (plain bf16 nn_w2, 1 MB) aliases qstar: read only during MP; qstar used after.
    __hip_bfloat16* w2r = (__hip_bfloat16*)qstar;

    // prep
    hipMemsetAsync(invdeg, 0, (size_t)NN * 4, stream);
    transpose_kernel<<<(192 * 64 + 255) / 256, 256, 0, stream>>>(gru_w_ih, gruT_ih, 192, 64);
    transpose_kernel<<<(192 * 64 + 255) / 256, 256, 0, stream>>>(gru_w_hh, gruT_hh, 192, 64);
    transpose_kernel<<<(256 * 128 + 255) / 256, 256, 0, stream>>>(s2s_w_ih, s2sT_ih, 256, 128);
    transpose_kernel<<<(256 * 64 + 255) / 256, 256, 0, stream>>>(s2s_w_hh, s2sT_hh, 256, 64);
    cvt_bf16_kernel<<<(64 * 8192 + 255) / 256, 256, 0, stream>>>(nn_w2, w2r, 64 * 8192);
    lin0_kernel<<<NN / 4, 256, 0, stream>>>(x, lin0_w, lin0_b, h);
    deg_kernel<<<(NE + 255) / 256, 256, 0, stream>>>(edge_index, invdeg);
    invdeg_kernel<<<(NN + 255) / 256, 256, 0, stream>>>(invdeg);
    starts_kernel<<<(NN + 255) / 256, 256, 0, stream>>>(batch, start);

    // 3 message-passing + conv+GRU iterations
    for (int it = 0; it < 3; it++) {
        hipMemsetAsync(agg, 0, (size_t)NN * D * 4, stream);
        msg_mfma_kernel<<<(NE + EB - 1) / EB, 512, 0, stream>>>(
            h, edge_attr, nn_w1, nn_b1, w2r, nn_b2, edge_index, agg);
        conv_gru_kernel<<<(NN + 31) / 32, 512, 0, stream>>>(
            h, agg, invdeg, conv_root, conv_bias, gruT_ih, gruT_hh, gru_b_ih, gru_b_hh);
    }

    // Set2Set (qstar region no longer needed as w2r)
    hipMemsetAsync(qstar, 0, (size_t)NG * 128 * 4, stream);
    hipMemsetAsync(hh, 0, (size_t)NG * 64 * 4, stream);
    hipMemsetAsync(ccv, 0, (size_t)NG * 64 * 4, stream);
    for (int t = 0; t < 3; t++) {
        s2s_lstm_kernel<<<NG, 256, 0, stream>>>(qstar, hh, ccv, s2sT_ih, s2sT_hh, s2s_b_ih, s2s_b_hh);
        s2s_attn_kernel<<<NG, 256, 0, stream>>>(h, hh, start, qstar);
    }
    final_kernel<<<NG, 64, 0, stream>>>(qstar, lin1_w, lin1_b, lin2_w, lin2_b, y);
}